// Round 5
// baseline (195.604 us; speedup 1.0000x reference)
//
#include <hip/hip_runtime.h>
#include <hip/hip_bf16.h>
#include <math.h>

// Problem constants (fixed by setup_inputs)
#define BB 2
#define HH 8
#define LQ 512
#define LK 512
#define DD 32

#define LOG2E 1.44269504088896f

static __device__ __forceinline__ float fast_rcp(float x) {
#if __has_builtin(__builtin_amdgcn_rcpf)
  return __builtin_amdgcn_rcpf(x);   // v_rcp_f32
#else
  return 1.0f / x;
#endif
}

static __device__ __forceinline__ float fast_exp2(float x) {
#if __has_builtin(__builtin_amdgcn_exp2f)
  return __builtin_amdgcn_exp2f(x);  // v_exp_f32
#else
  return __expf(x * 0.69314718056f);
#endif
}

static __device__ __forceinline__ float rfl(float x) {
  // wave-uniform value -> SGPR (frees the VALU operand slot, halves VGPR use)
  return __int_as_float(__builtin_amdgcn_readfirstlane(__float_as_int(x)));
}

// ---------------------------------------------------------------------------
// Pre-kernel: for each (b,h,kk,d): Ek = e^{-k}, ka = k*a[h][d], interleaved
// float2 into ws. 65536 threads, one float4 of k each. ~2 us.
// ---------------------------------------------------------------------------
__global__ __launch_bounds__(256) void gatv2_prek(
    const float* __restrict__ k, const float* __restrict__ att,
    float2* __restrict__ ws2) {
  const int idx = blockIdx.x * 256 + threadIdx.x;  // quad index, [0, 65536)
  const int d4 = idx & 7;                          // which float4 within d (32/4)
  const int row = idx >> 3;                        // (b*H+h)*LK + kk
  const int h = (row >> 9) & (HH - 1);

  const float4 kv = ((const float4*)k)[idx];
  const float4 av = ((const float4*)(att + h * DD))[d4];

  float4 o0, o1;  // {Ek0, ka0, Ek1, ka1}, {Ek2, ka2, Ek3, ka3}
  o0.x = fast_exp2(-kv.x * LOG2E); o0.y = kv.x * av.x;
  o0.z = fast_exp2(-kv.y * LOG2E); o0.w = kv.y * av.y;
  o1.x = fast_exp2(-kv.z * LOG2E); o1.y = kv.z * av.z;
  o1.z = fast_exp2(-kv.w * LOG2E); o1.w = kv.w * av.w;

  float4* o = (float4*)ws2;
  o[idx * 2 + 0] = o0;
  o[idx * 2 + 1] = o1;
}

// ---------------------------------------------------------------------------
// Main kernel: one wave per q-row; lane owns 8 k-columns.
// Per element: acc = fma(qa+ka, rcp(fma(Eq,Ek,1)), acc)  [3 VALU + 1 trans]
// ---------------------------------------------------------------------------
__global__ __launch_bounds__(256) void gatv2_main(
    const float* __restrict__ q, const int* __restrict__ mask,
    const float* __restrict__ bias, const float* __restrict__ att,
    const float2* __restrict__ ws2, float* __restrict__ out) {
  const int lane = threadIdx.x & 63;
  const int wid = threadIdx.x >> 6;
  const int r = blockIdx.x * 4 + wid;       // ((b*H)+h)*LQ + qi
  const int b = r >> 12;
  const int h = (r >> 9) & (HH - 1);
  const int qi = r & (LQ - 1);

  const float* __restrict__ qrow = q + (size_t)r * DD;
  const float* __restrict__ arow = att + h * DD;
  const float* __restrict__ brow = bias + (size_t)r * LK;
  const int* __restrict__ mrow = mask + ((size_t)(b * LQ + qi)) * LK;
  const float2* __restrict__ kb2 = ws2 + ((size_t)(b * HH + h)) * (size_t)(LK * DD);

  // Row-uniform per-d constants, hoisted to SGPRs.
  float sEq[DD], sQa[DD];
#pragma unroll
  for (int d0 = 0; d0 < DD; d0 += 4) {
    const float4 qq = *(const float4*)(qrow + d0);
    const float4 aa = *(const float4*)(arow + d0);
    const float qf[4] = {qq.x, qq.y, qq.z, qq.w};
    const float af[4] = {aa.x, aa.y, aa.z, aa.w};
#pragma unroll
    for (int j = 0; j < 4; ++j) {
      sEq[d0 + j] = rfl(fast_exp2(-qf[j] * LOG2E));
      sQa[d0 + j] = rfl(qf[j] * af[j]);
    }
  }

  float sc[8];
#pragma unroll
  for (int c = 0; c < 8; ++c) {
    const int kk = lane + 64 * c;
    const float2* __restrict__ kr2 = kb2 + (size_t)kk * DD;
    const float bval = brow[kk];            // coalesced
    const int mval = mrow[kk];              // coalesced
    float acc0 = 0.0f, acc1 = 0.0f;
#pragma unroll
    for (int d0 = 0; d0 < DD; d0 += 4) {
      const float4 e01 = *(const float4*)(kr2 + d0);      // Ek0 ka0 Ek1 ka1
      const float4 e23 = *(const float4*)(kr2 + d0 + 2);  // Ek2 ka2 Ek3 ka3
      const float u0 = fmaf(sEq[d0 + 0], e01.x, 1.0f);
      const float t0 = sQa[d0 + 0] + e01.y;
      acc0 = fmaf(t0, fast_rcp(u0), acc0);
      const float u1 = fmaf(sEq[d0 + 1], e01.z, 1.0f);
      const float t1 = sQa[d0 + 1] + e01.w;
      acc1 = fmaf(t1, fast_rcp(u1), acc1);
      const float u2 = fmaf(sEq[d0 + 2], e23.x, 1.0f);
      const float t2 = sQa[d0 + 2] + e23.y;
      acc0 = fmaf(t2, fast_rcp(u2), acc0);
      const float u3 = fmaf(sEq[d0 + 3], e23.z, 1.0f);
      const float t3 = sQa[d0 + 3] + e23.w;
      acc1 = fmaf(t3, fast_rcp(u3), acc1);
    }
    const float s = (acc0 + acc1) + bval;
    sc[c] = mval ? -INFINITY : s;
  }

  // Wave-wide softmax over the 512 columns (8 per lane)
  float m = sc[0];
#pragma unroll
  for (int c = 1; c < 8; ++c) m = fmaxf(m, sc[c]);
#pragma unroll
  for (int off = 32; off > 0; off >>= 1)
    m = fmaxf(m, __shfl_xor(m, off, 64));

  float sum = 0.0f;
#pragma unroll
  for (int c = 0; c < 8; ++c) {
    const float p = fast_exp2((sc[c] - m) * LOG2E);
    sc[c] = p;
    sum += p;
  }
#pragma unroll
  for (int off = 32; off > 0; off >>= 1)
    sum += __shfl_xor(sum, off, 64);

  const bool dead = (m == -INFINITY);
  const float inv = dead ? 0.0f : fast_rcp(sum);

  float* __restrict__ orow = out + (size_t)r * LK;
#pragma unroll
  for (int c = 0; c < 8; ++c) {
    orow[lane + 64 * c] = dead ? 0.0f : sc[c] * inv;
  }
}

// ---------------------------------------------------------------------------
// Fallback (proven R2 kernel) in case ws_size < 2 MB.
// ---------------------------------------------------------------------------
__global__ __launch_bounds__(256) void gatv2_fallback(
    const float* __restrict__ q, const float* __restrict__ k,
    const int* __restrict__ mask, const float* __restrict__ bias,
    const float* __restrict__ att, float* __restrict__ out) {
  const int lane = threadIdx.x & 63;
  const int wid = threadIdx.x >> 6;
  const int r = blockIdx.x * 4 + wid;
  const int b = r >> 12;
  const int h = (r >> 9) & (HH - 1);
  const int qi = r & (LQ - 1);

  const float* __restrict__ qrow = q + (size_t)r * DD;
  const float* __restrict__ kbase = k + ((size_t)(b * HH + h)) * (size_t)(LK * DD);
  const float* __restrict__ arow = att + h * DD;
  const float* __restrict__ brow = bias + (size_t)r * LK;
  const int* __restrict__ mrow = mask + ((size_t)(b * LQ + qi)) * LK;

  float qv[DD], av[DD];
#pragma unroll
  for (int d0 = 0; d0 < DD; d0 += 4) {
    const float4 qq = *(const float4*)(qrow + d0);
    const float4 aa = *(const float4*)(arow + d0);
    qv[d0 + 0] = qq.x; qv[d0 + 1] = qq.y; qv[d0 + 2] = qq.z; qv[d0 + 3] = qq.w;
    av[d0 + 0] = aa.x; av[d0 + 1] = aa.y; av[d0 + 2] = aa.z; av[d0 + 3] = aa.w;
  }

  float sc[8];
#pragma unroll
  for (int c = 0; c < 8; ++c) {
    const int kk = lane + 64 * c;
    const float* __restrict__ kr = kbase + (size_t)kk * DD;
    const float bval = brow[kk];
    const int mval = mrow[kk];
    float acc = 0.0f;
#pragma unroll
    for (int d0 = 0; d0 < DD; d0 += 4) {
      const float4 kv = *(const float4*)(kr + d0);
      const float kvf[4] = {kv.x, kv.y, kv.z, kv.w};
#pragma unroll
      for (int j = 0; j < 4; ++j) {
        const float t = qv[d0 + j] + kvf[j];
        const float e = fast_exp2(t * -LOG2E);
        const float sg = fast_rcp(1.0f + e);
        acc = fmaf(t * sg, av[d0 + j], acc);
      }
    }
    const float s = acc + bval;
    sc[c] = mval ? -INFINITY : s;
  }

  float m = sc[0];
#pragma unroll
  for (int c = 1; c < 8; ++c) m = fmaxf(m, sc[c]);
#pragma unroll
  for (int off = 32; off > 0; off >>= 1)
    m = fmaxf(m, __shfl_xor(m, off, 64));

  float sum = 0.0f;
#pragma unroll
  for (int c = 0; c < 8; ++c) {
    const float p = fast_exp2((sc[c] - m) * LOG2E);
    sc[c] = p;
    sum += p;
  }
#pragma unroll
  for (int off = 32; off > 0; off >>= 1)
    sum += __shfl_xor(sum, off, 64);

  const bool dead = (m == -INFINITY);
  const float inv = dead ? 0.0f : fast_rcp(sum);

  float* __restrict__ orow = out + (size_t)r * LK;
#pragma unroll
  for (int c = 0; c < 8; ++c) {
    orow[lane + 64 * c] = dead ? 0.0f : sc[c] * inv;
  }
}

extern "C" void kernel_launch(void* const* d_in, const int* in_sizes, int n_in,
                              void* d_out, int out_size, void* d_ws, size_t ws_size,
                              hipStream_t stream) {
  const float* q = (const float*)d_in[0];
  const float* k = (const float*)d_in[1];
  // d_in[2] = scale, unused by the reference module
  const int* mask = (const int*)d_in[3];
  const float* bias = (const float*)d_in[4];
  const float* att = (const float*)d_in[5];
  float* out = (float*)d_out;

  const int rows = BB * HH * LQ;            // 8192 rows
  const size_t ws_needed = (size_t)BB * HH * LK * DD * sizeof(float2);  // 2 MB

  if (ws_size >= ws_needed) {
    float2* ws2 = (float2*)d_ws;
    // Pre-kernel: 65536 quads / 256 threads = 256 blocks
    gatv2_prek<<<dim3(256), dim3(256), 0, stream>>>(k, att, ws2);
    gatv2_main<<<dim3(rows / 4), dim3(256), 0, stream>>>(q, mask, bias, att, ws2, out);
  } else {
    gatv2_fallback<<<dim3(rows / 4), dim3(256), 0, stream>>>(q, k, mask, bias, att, out);
  }
}

// Round 6
// 142.339 us; speedup vs baseline: 1.3742x; 1.3742x over previous
//
#include <hip/hip_runtime.h>
#include <hip/hip_bf16.h>
#include <math.h>

// Problem constants (fixed by setup_inputs)
#define BB 2
#define HH 8
#define LQ 512
#define LK 512
#define DD 32

#define LOG2E 1.44269504088896f

static __device__ __forceinline__ float fast_rcp(float x) {
#if __has_builtin(__builtin_amdgcn_rcpf)
  return __builtin_amdgcn_rcpf(x);   // v_rcp_f32
#else
  return 1.0f / x;
#endif
}

static __device__ __forceinline__ float fast_exp2(float x) {
#if __has_builtin(__builtin_amdgcn_exp2f)
  return __builtin_amdgcn_exp2f(x);  // v_exp_f32
#else
  return __expf(x * 0.69314718056f);
#endif
}

static __device__ __forceinline__ float rfl(float x) {
  // wave-uniform value -> SGPR
  return __int_as_float(__builtin_amdgcn_readfirstlane(__float_as_int(x)));
}

// ---------------------------------------------------------------------------
// Pre-kernel (transposing): wst[bh][d][kk] = {Ek=e^{-k}, ka=k*a[h][d]} float2.
// LDS-transpose tile so both global read and write are coalesced.
// Grid: 16 bh * 8 kk-tiles = 128 blocks x 256 threads.
// ---------------------------------------------------------------------------
__global__ __launch_bounds__(256) void gatv2_prek_t(
    const float* __restrict__ k, const float* __restrict__ att,
    float2* __restrict__ wst) {
  const int bh = blockIdx.x >> 3;          // 0..15
  const int kt = blockIdx.x & 7;           // kk tile of 64
  const int h = bh & (HH - 1);
  const int t = threadIdx.x;

  __shared__ float tile[64][33];           // +1 pad: conflict-free transpose

  // Load 64 kk x 32 d, coalesced float4 (512 float4s, 2 per thread)
  const float4* src = (const float4*)(k + ((size_t)bh * LK + kt * 64) * DD);
#pragma unroll
  for (int i = 0; i < 2; ++i) {
    const int idx = t + i * 256;           // 0..511
    const float4 v = src[idx];
    const int kkl = idx >> 3;              // 8 float4 per kk-row
    const int d4 = (idx & 7) * 4;
    tile[kkl][d4 + 0] = v.x; tile[kkl][d4 + 1] = v.y;
    tile[kkl][d4 + 2] = v.z; tile[kkl][d4 + 3] = v.w;
  }
  __syncthreads();

  // Each thread: one d, 8 consecutive kk -> coalesced float2 stores
  const int d = t >> 3;                    // 0..31
  const int kl0 = (t & 7) * 8;             // 0..56
  const float a = att[h * DD + d];
  float2* dst = wst + ((size_t)bh * DD + d) * LK + kt * 64 + kl0;
#pragma unroll
  for (int j = 0; j < 8; ++j) {
    const float kv = tile[kl0 + j][d];
    float2 o;
    o.x = fast_exp2(-kv * LOG2E);
    o.y = kv * a;
    dst[j] = o;
  }
}

// ---------------------------------------------------------------------------
// Main kernel: one wave per q-row; lane owns 8 k-columns (kk = lane + 64c).
// Coalesced float2 loads from transposed wst. Per element:
//   u = fma(Eq, Ek, 1); t = qa + ka; acc = fma(t, rcp(u), acc)
// ---------------------------------------------------------------------------
__global__ __launch_bounds__(256) void gatv2_main_t(
    const float* __restrict__ q, const int* __restrict__ mask,
    const float* __restrict__ bias, const float* __restrict__ att,
    const float2* __restrict__ wst, float* __restrict__ out) {
  const int lane = threadIdx.x & 63;
  const int wid = threadIdx.x >> 6;
  const int r = blockIdx.x * 4 + wid;      // ((b*H)+h)*LQ + qi
  const int b = r >> 12;
  const int h = (r >> 9) & (HH - 1);
  const int qi = r & (LQ - 1);

  const float* __restrict__ qrow = q + (size_t)r * DD;
  const float* __restrict__ arow = att + h * DD;
  const float* __restrict__ brow = bias + (size_t)r * LK;
  const int* __restrict__ mrow = mask + ((size_t)(b * LQ + qi)) * LK;
  const float2* __restrict__ kb = wst + (size_t)(b * HH + h) * (size_t)(DD * LK);

  // Row-uniform per-d constants -> SGPRs
  float sEq[DD], sQa[DD];
#pragma unroll
  for (int d0 = 0; d0 < DD; d0 += 4) {
    const float4 qq = *(const float4*)(qrow + d0);
    const float4 aa = *(const float4*)(arow + d0);
    const float qf[4] = {qq.x, qq.y, qq.z, qq.w};
    const float af[4] = {aa.x, aa.y, aa.z, aa.w};
#pragma unroll
    for (int j = 0; j < 4; ++j) {
      sEq[d0 + j] = rfl(fast_exp2(-qf[j] * LOG2E));
      sQa[d0 + j] = rfl(qf[j] * af[j]);
    }
  }

  float acc[8];
  float bv[8];
  int mv[8];
#pragma unroll
  for (int c = 0; c < 8; ++c) {
    acc[c] = 0.0f;
    bv[c] = brow[lane + 64 * c];           // coalesced
    mv[c] = mrow[lane + 64 * c];           // coalesced
  }

#pragma unroll
  for (int d = 0; d < DD; ++d) {
    const float2* __restrict__ pd = kb + d * LK + lane;
    const float eq = sEq[d];
    const float qa = sQa[d];
#pragma unroll
    for (int c = 0; c < 8; ++c) {
      const float2 p = pd[64 * c];         // coalesced dwordx2, imm offset
      const float u = fmaf(eq, p.x, 1.0f);
      const float t = qa + p.y;
      acc[c] = fmaf(t, fast_rcp(u), acc[c]);
    }
  }

  float sc[8];
#pragma unroll
  for (int c = 0; c < 8; ++c)
    sc[c] = mv[c] ? -INFINITY : (acc[c] + bv[c]);

  // Wave-wide softmax over 512 columns (8 per lane)
  float m = sc[0];
#pragma unroll
  for (int c = 1; c < 8; ++c) m = fmaxf(m, sc[c]);
#pragma unroll
  for (int off = 32; off > 0; off >>= 1)
    m = fmaxf(m, __shfl_xor(m, off, 64));

  float sum = 0.0f;
#pragma unroll
  for (int c = 0; c < 8; ++c) {
    const float p = fast_exp2((sc[c] - m) * LOG2E);
    sc[c] = p;
    sum += p;
  }
#pragma unroll
  for (int off = 32; off > 0; off >>= 1)
    sum += __shfl_xor(sum, off, 64);

  const bool dead = (m == -INFINITY);
  const float inv = dead ? 0.0f : fast_rcp(sum);

  float* __restrict__ orow = out + (size_t)r * LK;
#pragma unroll
  for (int c = 0; c < 8; ++c) {
    orow[lane + 64 * c] = dead ? 0.0f : sc[c] * inv;
  }
}

// ---------------------------------------------------------------------------
// Fallback (proven R2 kernel) in case ws_size < 2 MB.
// ---------------------------------------------------------------------------
__global__ __launch_bounds__(256) void gatv2_fallback(
    const float* __restrict__ q, const float* __restrict__ k,
    const int* __restrict__ mask, const float* __restrict__ bias,
    const float* __restrict__ att, float* __restrict__ out) {
  const int lane = threadIdx.x & 63;
  const int wid = threadIdx.x >> 6;
  const int r = blockIdx.x * 4 + wid;
  const int b = r >> 12;
  const int h = (r >> 9) & (HH - 1);
  const int qi = r & (LQ - 1);

  const float* __restrict__ qrow = q + (size_t)r * DD;
  const float* __restrict__ kbase = k + ((size_t)(b * HH + h)) * (size_t)(LK * DD);
  const float* __restrict__ arow = att + h * DD;
  const float* __restrict__ brow = bias + (size_t)r * LK;
  const int* __restrict__ mrow = mask + ((size_t)(b * LQ + qi)) * LK;

  float qv[DD], av[DD];
#pragma unroll
  for (int d0 = 0; d0 < DD; d0 += 4) {
    const float4 qq = *(const float4*)(qrow + d0);
    const float4 aa = *(const float4*)(arow + d0);
    qv[d0 + 0] = qq.x; qv[d0 + 1] = qq.y; qv[d0 + 2] = qq.z; qv[d0 + 3] = qq.w;
    av[d0 + 0] = aa.x; av[d0 + 1] = aa.y; av[d0 + 2] = aa.z; av[d0 + 3] = aa.w;
  }

  float sc[8];
#pragma unroll
  for (int c = 0; c < 8; ++c) {
    const int kk = lane + 64 * c;
    const float* __restrict__ kr = kbase + (size_t)kk * DD;
    const float bval = brow[kk];
    const int mval = mrow[kk];
    float acc = 0.0f;
#pragma unroll
    for (int d0 = 0; d0 < DD; d0 += 4) {
      const float4 kv = *(const float4*)(kr + d0);
      const float kvf[4] = {kv.x, kv.y, kv.z, kv.w};
#pragma unroll
      for (int j = 0; j < 4; ++j) {
        const float t = qv[d0 + j] + kvf[j];
        const float e = fast_exp2(t * -LOG2E);
        const float sg = fast_rcp(1.0f + e);
        acc = fmaf(t * sg, av[d0 + j], acc);
      }
    }
    const float s = acc + bval;
    sc[c] = mval ? -INFINITY : s;
  }

  float m = sc[0];
#pragma unroll
  for (int c = 1; c < 8; ++c) m = fmaxf(m, sc[c]);
#pragma unroll
  for (int off = 32; off > 0; off >>= 1)
    m = fmaxf(m, __shfl_xor(m, off, 64));

  float sum = 0.0f;
#pragma unroll
  for (int c = 0; c < 8; ++c) {
    const float p = fast_exp2((sc[c] - m) * LOG2E);
    sc[c] = p;
    sum += p;
  }
#pragma unroll
  for (int off = 32; off > 0; off >>= 1)
    sum += __shfl_xor(sum, off, 64);

  const bool dead = (m == -INFINITY);
  const float inv = dead ? 0.0f : fast_rcp(sum);

  float* __restrict__ orow = out + (size_t)r * LK;
#pragma unroll
  for (int c = 0; c < 8; ++c) {
    orow[lane + 64 * c] = dead ? 0.0f : sc[c] * inv;
  }
}

extern "C" void kernel_launch(void* const* d_in, const int* in_sizes, int n_in,
                              void* d_out, int out_size, void* d_ws, size_t ws_size,
                              hipStream_t stream) {
  const float* q = (const float*)d_in[0];
  const float* k = (const float*)d_in[1];
  // d_in[2] = scale, unused by the reference module
  const int* mask = (const int*)d_in[3];
  const float* bias = (const float*)d_in[4];
  const float* att = (const float*)d_in[5];
  float* out = (float*)d_out;

  const int rows = BB * HH * LQ;            // 8192 rows
  const size_t ws_needed = (size_t)BB * HH * LK * DD * sizeof(float2);  // 2 MB

  if (ws_size >= ws_needed) {
    float2* wst = (float2*)d_ws;
    gatv2_prek_t<<<dim3(128), dim3(256), 0, stream>>>(k, att, wst);
    gatv2_main_t<<<dim3(rows / 4), dim3(256), 0, stream>>>(q, mask, bias, att, wst, out);
  } else {
    gatv2_fallback<<<dim3(rows / 4), dim3(256), 0, stream>>>(q, k, mask, bias, att, out);
  }
}